// Round 6
// baseline (221.201 us; speedup 1.0000x reference)
//
#include <hip/hip_runtime.h>

#define CH 128          // channels
#define CHUNK 8192      // edges per sort chunk
#define BSH 10          // 1024 nodes per bucket
#define BNODES 1024
#define MAXB 128        // max buckets supported (n <= 131072)
#define SLICES 4        // agg slices per bucket

// ---- K0: u[r] = W1[r,:].W2 (r<128) ; u[128] = beta = b1.W2 -----------------
__global__ __launch_bounds__(256) void k_uw(const float* __restrict__ W1,
                                            const float* __restrict__ b1,
                                            const float* __restrict__ W2,
                                            float* __restrict__ u) {
    int wid  = blockIdx.x * 4 + (threadIdx.x >> 6);
    if (wid > CH) return;
    int lane = threadIdx.x & 63;
    const float* rowp = (wid < CH) ? (W1 + (size_t)wid * CH) : b1;
    float2 xv = *(const float2*)(rowp + lane * 2);
    float2 vv = *(const float2*)(W2 + lane * 2);
    float acc = xv.x * vv.x + xv.y * vv.y;
#pragma unroll
    for (int m = 32; m; m >>= 1) acc += __shfl_xor(acc, m);
    if (lane == 0) u[wid] = acc;
}

// ---- K1: t[i] = x[i,:].u  — float4, 2 rows per wave ------------------------
__global__ __launch_bounds__(256) void k_gemv(const float* __restrict__ X,
                                              const float* __restrict__ v,
                                              float* __restrict__ t, int n) {
    int wv   = blockIdx.x * 4 + (threadIdx.x >> 6);
    int lane = threadIdx.x & 63;
    int row  = wv * 2 + (lane >> 5);
    if (row >= n) return;
    float4 xv = *(const float4*)(X + (size_t)row * CH + (lane & 31) * 4);
    float4 vv = *(const float4*)(v + (lane & 31) * 4);
    float acc = xv.x * vv.x + xv.y * vv.y + xv.z * vv.z + xv.w * vv.w;
#pragma unroll
    for (int m = 16; m; m >>= 1) acc += __shfl_xor(acc, m);
    if ((lane & 31) == 0) t[row] = acc;
}

// ---- K2: per-chunk bucket histogram -> Ht[chunk][bucket] -------------------
__global__ __launch_bounds__(256) void k_hist(const int* __restrict__ col,
                                              int* __restrict__ Ht,
                                              int nbuck, int e_cnt) {
    __shared__ int h[MAXB];
    int b = blockIdx.x, tid = threadIdx.x;
    if (tid < nbuck) h[tid] = 0;
    __syncthreads();
    int e0 = b * CHUNK, e1 = min(e0 + CHUNK, e_cnt);
    for (int e = e0 + tid; e < e1; e += 256)
        atomicAdd(&h[col[e] >> BSH], 1);
    __syncthreads();
    if (tid < nbuck) Ht[(size_t)b * nbuck + tid] = h[tid];
}

// ---- K3: fused scan: per-column exclusive scan of Ht + bucket bases --------
// one block; thread j owns column j (coalesced row-wise access)
__global__ __launch_bounds__(128) void k_scan(int* __restrict__ Ht,
                                              int* __restrict__ bstart,
                                              int nchunk, int nbuck) {
    __shared__ int tot[MAXB];
    __shared__ int base[MAXB + 1];
    int j = threadIdx.x;
    if (j < nbuck) {
        int run = 0;
        for (int c = 0; c < nchunk; ++c) {
            size_t idx = (size_t)c * nbuck + j;
            int v = Ht[idx];
            Ht[idx] = run;
            run += v;
        }
        tot[j] = run;
    }
    __syncthreads();
    if (j == 0) {
        int running = 0;
        for (int k = 0; k < nbuck; ++k) { base[k] = running; running += tot[k]; }
        base[nbuck] = running;
    }
    __syncthreads();
    if (j <= nbuck) bstart[j] = base[j];
}

// ---- K4: permute edges into bucket-sorted int2 (key, w) --------------------
__global__ __launch_bounds__(256) void k_permute(const int* __restrict__ row,
                                                 const int* __restrict__ col,
                                                 const float* __restrict__ w,
                                                 const int* __restrict__ Ht,
                                                 const int* __restrict__ bstart,
                                                 int2* __restrict__ ep,
                                                 int nbuck, int e_cnt) {
    __shared__ int cur[MAXB];
    int b = blockIdx.x, tid = threadIdx.x;
    if (tid < nbuck) cur[tid] = bstart[tid] + Ht[(size_t)b * nbuck + tid];
    __syncthreads();
    int e0 = b * CHUNK, e1 = min(e0 + CHUNK, e_cnt);
    for (int e = e0 + tid; e < e1; e += 256) {
        int r = row[e], c = col[e];
        float wv = w[e];
        int pos = atomicAdd(&cur[c >> BSH], 1);
        ep[pos] = make_int2(r | ((c & (BNODES - 1)) << 17), __float_as_int(wv));
    }
}

// ---- K5a: deg partials: part[(b*S+s)][local] = sum of w into local ---------
__global__ __launch_bounds__(256) void k_adeg(const int2* __restrict__ ep,
                                              const int* __restrict__ bstart,
                                              float* __restrict__ part) {
    __shared__ float acc[BNODES];
    int bx = blockIdx.x, tid = threadIdx.x;
    int b = bx / SLICES, s = bx % SLICES;
#pragma unroll
    for (int k = 0; k < BNODES / 256; ++k) acc[tid + k * 256] = 0.f;
    __syncthreads();
    int start = bstart[b], len = bstart[b + 1] - start;
    int j0 = start + (int)((long long)len * s / SLICES);
    int j1 = start + (int)((long long)len * (s + 1) / SLICES);
    for (int j = j0 + tid; j < j1; j += 256) {
        int2 kv = ep[j];
        atomicAdd(&acc[kv.x >> 17], __int_as_float(kv.y));
    }
    __syncthreads();
    float* outp = part + (size_t)bx * BNODES;
#pragma unroll
    for (int k = 0; k < BNODES / 256; ++k) outp[tid + k * 256] = acc[tid + k * 256];
}

// ---- K5b: merge deg -> dinv, p = dinv*t ------------------------------------
__global__ __launch_bounds__(256) void k_mdeg(const float* __restrict__ part,
                                              const float* __restrict__ t,
                                              float* __restrict__ dinv,
                                              float* __restrict__ p, int n) {
    int i = blockIdx.x * 256 + threadIdx.x;
    if (i >= n) return;
    int b = i >> BSH, local = i & (BNODES - 1);
    float deg = 1.0f;   // self-loop
#pragma unroll
    for (int s = 0; s < SLICES; ++s)
        deg += part[((size_t)b * SLICES + s) * BNODES + local];
    float di = rsqrtf(deg);
    dinv[i] = di;
    p[i] = di * t[i];
}

// ---- K6a: s1 partials: sum of w * p[src] -----------------------------------
__global__ __launch_bounds__(256) void k_as1(const int2* __restrict__ ep,
                                             const int* __restrict__ bstart,
                                             const float* __restrict__ p,
                                             float* __restrict__ part) {
    __shared__ float acc[BNODES];
    int bx = blockIdx.x, tid = threadIdx.x;
    int b = bx / SLICES, s = bx % SLICES;
#pragma unroll
    for (int k = 0; k < BNODES / 256; ++k) acc[tid + k * 256] = 0.f;
    __syncthreads();
    int start = bstart[b], len = bstart[b + 1] - start;
    int j0 = start + (int)((long long)len * s / SLICES);
    int j1 = start + (int)((long long)len * (s + 1) / SLICES);
    for (int j = j0 + tid; j < j1; j += 256) {
        int2 kv = ep[j];
        atomicAdd(&acc[kv.x >> 17], __int_as_float(kv.y) * p[kv.x & 0x1FFFF]);
    }
    __syncthreads();
    float* outp = part + (size_t)bx * BNODES;
#pragma unroll
    for (int k = 0; k < BNODES / 256; ++k) outp[tid + k * 256] = acc[tid + k * 256];
}

// ---- K6b: merge s1 -> q = dinv*(s1+beta) -----------------------------------
__global__ __launch_bounds__(256) void k_ms1(const float* __restrict__ part,
                                             const float* __restrict__ p,
                                             const float* __restrict__ dinv,
                                             const float* __restrict__ u,
                                             float* __restrict__ q, int n) {
    int i = blockIdx.x * 256 + threadIdx.x;
    if (i >= n) return;
    int b = i >> BSH, local = i & (BNODES - 1);
    float acc = p[i];   // self-loop term dinv*t = p
#pragma unroll
    for (int s = 0; s < SLICES; ++s)
        acc += part[((size_t)b * SLICES + s) * BNODES + local];
    float di = dinv[i];
    float s1 = di * acc;
    q[i] = di * (s1 + u[CH]);
}

// ---- K7a: out partials: sum of w * q[src] ----------------------------------
__global__ __launch_bounds__(256) void k_aout(const int2* __restrict__ ep,
                                              const int* __restrict__ bstart,
                                              const float* __restrict__ q,
                                              float* __restrict__ part) {
    __shared__ float acc[BNODES];
    int bx = blockIdx.x, tid = threadIdx.x;
    int b = bx / SLICES, s = bx % SLICES;
#pragma unroll
    for (int k = 0; k < BNODES / 256; ++k) acc[tid + k * 256] = 0.f;
    __syncthreads();
    int start = bstart[b], len = bstart[b + 1] - start;
    int j0 = start + (int)((long long)len * s / SLICES);
    int j1 = start + (int)((long long)len * (s + 1) / SLICES);
    for (int j = j0 + tid; j < j1; j += 256) {
        int2 kv = ep[j];
        atomicAdd(&acc[kv.x >> 17], __int_as_float(kv.y) * q[kv.x & 0x1FFFF]);
    }
    __syncthreads();
    float* outp = part + (size_t)bx * BNODES;
#pragma unroll
    for (int k = 0; k < BNODES / 256; ++k) outp[tid + k * 256] = acc[tid + k * 256];
}

// ---- K7b: merge out = b2 + dinv*(q + sum) ----------------------------------
__global__ __launch_bounds__(256) void k_mout(const float* __restrict__ part,
                                              const float* __restrict__ q,
                                              const float* __restrict__ dinv,
                                              const float* __restrict__ b2,
                                              float* __restrict__ out, int n) {
    int i = blockIdx.x * 256 + threadIdx.x;
    if (i >= n) return;
    int b = i >> BSH, local = i & (BNODES - 1);
    float acc = q[i];   // self-loop term
#pragma unroll
    for (int s = 0; s < SLICES; ++s)
        acc += part[((size_t)b * SLICES + s) * BNODES + local];
    out[i] = b2[0] + dinv[i] * acc;
}

extern "C" void kernel_launch(void* const* d_in, const int* in_sizes, int n_in,
                              void* d_out, int out_size, void* d_ws, size_t ws_size,
                              hipStream_t stream) {
    const float* x   = (const float*)d_in[0];
    const int*   ei  = (const int*)d_in[1];
    const float* w   = (const float*)d_in[2];
    const float* W1  = (const float*)d_in[3];
    const float* b1  = (const float*)d_in[4];
    const float* W2  = (const float*)d_in[5];
    const float* b2  = (const float*)d_in[6];
    float* out = (float*)d_out;

    const int n     = in_sizes[0] / CH;    // 100000
    const int e_cnt = in_sizes[2];         // 1600000
    const int* row = ei;
    const int* col = ei + e_cnt;

    const int nbuck  = (n + BNODES - 1) >> BSH;         // 98
    const int nchunk = (e_cnt + CHUNK - 1) / CHUNK;     // 196

    // ---- workspace layout (ep first for 8B alignment) ----
    int2*  ep     = (int2*)d_ws;                        // e_cnt int2
    float* u      = (float*)(ep + e_cnt);               // 132
    float* t      = u + 132;                            // n
    float* dinv   = t + n;                              // n
    float* p      = dinv + n;                           // n
    float* q      = p + n;                              // n
    float* part   = q + n;                              // nbuck*SLICES*BNODES
    int*   bstart = (int*)(part + (size_t)nbuck * SLICES * BNODES); // nbuck+1
    int*   Ht     = bstart + nbuck + 2;                 // nchunk*nbuck

    k_uw<<<(CH + 1 + 3) / 4, 256, 0, stream>>>(W1, b1, W2, u);
    k_gemv<<<(n + 7) / 8, 256, 0, stream>>>(x, u, t, n);

    k_hist<<<nchunk, 256, 0, stream>>>(col, Ht, nbuck, e_cnt);
    k_scan<<<1, 128, 0, stream>>>(Ht, bstart, nchunk, nbuck);
    k_permute<<<nchunk, 256, 0, stream>>>(row, col, w, Ht, bstart, ep, nbuck, e_cnt);

    const int nagg = nbuck * SLICES;
    k_adeg<<<nagg, 256, 0, stream>>>(ep, bstart, part);
    k_mdeg<<<(n + 255) / 256, 256, 0, stream>>>(part, t, dinv, p, n);
    k_as1<<<nagg, 256, 0, stream>>>(ep, bstart, p, part);
    k_ms1<<<(n + 255) / 256, 256, 0, stream>>>(part, p, dinv, u, q, n);
    k_aout<<<nagg, 256, 0, stream>>>(ep, bstart, q, part);
    k_mout<<<(n + 255) / 256, 256, 0, stream>>>(part, q, dinv, b2, out, n);
}

// Round 7
// 174.282 us; speedup vs baseline: 1.2692x; 1.2692x over previous
//
#include <hip/hip_runtime.h>

#define CH 128          // channels
#define CHUNK 8192      // edges per sort chunk
#define BSH 9           // 512 nodes per bucket
#define BNODES 512
#define MAXB 256        // max buckets supported (n <= 131072)

// ---- K0: u[r] = W1[r,:].W2 (r<128) ; u[128] = beta = b1.W2 -----------------
__global__ __launch_bounds__(256) void k_uw(const float* __restrict__ W1,
                                            const float* __restrict__ b1,
                                            const float* __restrict__ W2,
                                            float* __restrict__ u) {
    int wid  = blockIdx.x * 4 + (threadIdx.x >> 6);
    if (wid > CH) return;
    int lane = threadIdx.x & 63;
    const float* rowp = (wid < CH) ? (W1 + (size_t)wid * CH) : b1;
    float2 xv = *(const float2*)(rowp + lane * 2);
    float2 vv = *(const float2*)(W2 + lane * 2);
    float acc = xv.x * vv.x + xv.y * vv.y;
#pragma unroll
    for (int m = 32; m; m >>= 1) acc += __shfl_xor(acc, m);
    if (lane == 0) u[wid] = acc;
}

// ---- K1: t[i] = x[i,:].u  — float4, 2 rows per wave ------------------------
__global__ __launch_bounds__(256) void k_gemv(const float* __restrict__ X,
                                              const float* __restrict__ v,
                                              float* __restrict__ t, int n) {
    int wv   = blockIdx.x * 4 + (threadIdx.x >> 6);
    int lane = threadIdx.x & 63;
    int row  = wv * 2 + (lane >> 5);
    if (row >= n) return;
    float4 xv = *(const float4*)(X + (size_t)row * CH + (lane & 31) * 4);
    float4 vv = *(const float4*)(v + (lane & 31) * 4);
    float acc = xv.x * vv.x + xv.y * vv.y + xv.z * vv.z + xv.w * vv.w;
#pragma unroll
    for (int m = 16; m; m >>= 1) acc += __shfl_xor(acc, m);
    if ((lane & 31) == 0) t[row] = acc;
}

// ---- K2: per-chunk bucket histogram -> Ht[chunk][bucket] -------------------
__global__ __launch_bounds__(256) void k_hist(const int* __restrict__ col,
                                              int* __restrict__ Ht,
                                              int nbuck, int e_cnt) {
    __shared__ int h[MAXB];
    int b = blockIdx.x, tid = threadIdx.x;
    if (tid < nbuck) h[tid] = 0;
    __syncthreads();
    int e0 = b * CHUNK, e1 = min(e0 + CHUNK, e_cnt);
    for (int e = e0 + tid; e < e1; e += 256)
        atomicAdd(&h[col[e] >> BSH], 1);
    __syncthreads();
    if (tid < nbuck) Ht[(size_t)b * nbuck + tid] = h[tid];
}

// ---- K3: per-column exclusive scan Ht -> Hs (separate array!), coltot ------
// wave per column; no load/store aliasing so loads pipeline freely
__global__ __launch_bounds__(256) void k_colscan(const int* __restrict__ Ht,
                                                 int* __restrict__ Hs,
                                                 int* __restrict__ coltot,
                                                 int nchunk, int nbuck) {
    int j = blockIdx.x * 4 + (threadIdx.x >> 6);
    if (j >= nbuck) return;
    int lane = threadIdx.x & 63;
    int run = 0;
    for (int base = 0; base < nchunk; base += 64) {
        int idx = base + lane;
        int v = (idx < nchunk) ? Ht[(size_t)idx * nbuck + j] : 0;
        int incl = v;
#pragma unroll
        for (int d = 1; d < 64; d <<= 1) {
            int up = __shfl_up(incl, d);
            if (lane >= d) incl += up;
        }
        if (idx < nchunk) Hs[(size_t)idx * nbuck + j] = run + incl - v;
        run += __shfl(incl, 63);
    }
    if (lane == 0) coltot[j] = run;
}

// ---- K4: permute edges -> bucket-sorted int2; block 0 publishes bstart -----
__global__ __launch_bounds__(256) void k_permute(const int* __restrict__ row,
                                                 const int* __restrict__ col,
                                                 const float* __restrict__ w,
                                                 const int* __restrict__ Hs,
                                                 const int* __restrict__ coltot,
                                                 int* __restrict__ bstart,
                                                 int2* __restrict__ ep,
                                                 int nbuck, int e_cnt) {
    __shared__ int ct[MAXB];
    __shared__ int bs[MAXB + 1];
    __shared__ int cur[MAXB];
    int b = blockIdx.x, tid = threadIdx.x;
    for (int k = tid; k < nbuck; k += 256) ct[k] = coltot[k];
    __syncthreads();
    if (tid < 64) {   // single-wave exclusive scan of nbuck (<=256) totals
        int vals[4]; int sum = 0;
#pragma unroll
        for (int k = 0; k < 4; ++k) {
            int idx = tid * 4 + k;
            vals[k] = (idx < nbuck) ? ct[idx] : 0;
            sum += vals[k];
        }
        int incl = sum;
#pragma unroll
        for (int d = 1; d < 64; d <<= 1) {
            int up = __shfl_up(incl, d);
            if (tid >= d) incl += up;
        }
        int run = incl - sum;   // exclusive prefix before this lane's 4 slots
#pragma unroll
        for (int k = 0; k < 4; ++k) {
            int idx = tid * 4 + k;
            if (idx < nbuck) bs[idx] = run;
            run += vals[k];
        }
        if (tid == 63) bs[nbuck] = run;   // grand total
    }
    __syncthreads();
    for (int k = tid; k < nbuck; k += 256) cur[k] = bs[k] + Hs[(size_t)b * nbuck + k];
    __syncthreads();
    int e0 = b * CHUNK, e1 = min(e0 + CHUNK, e_cnt);
    for (int e = e0 + tid; e < e1; e += 256) {
        int r = row[e], c = col[e];
        float wv = w[e];
        int pos = atomicAdd(&cur[c >> BSH], 1);
        ep[pos] = make_int2(r | ((c & (BNODES - 1)) << 17), __float_as_int(wv));
    }
    if (b == 0)
        for (int k = tid; k <= nbuck; k += 256) bstart[k] = bs[k];
}

// ---- K5: deg agg (one block owns bucket) -> dinv, p = dinv*t ---------------
__global__ __launch_bounds__(512) void k_adeg(const int2* __restrict__ ep,
                                              const int* __restrict__ bstart,
                                              const float* __restrict__ t,
                                              float* __restrict__ dinv,
                                              float* __restrict__ p, int n) {
    __shared__ float acc[BNODES];
    int b = blockIdx.x, tid = threadIdx.x;
    acc[tid] = 0.f;
    __syncthreads();
    int j1 = bstart[b + 1];
    for (int j = bstart[b] + tid; j < j1; j += 512) {
        int2 kv = ep[j];
        atomicAdd(&acc[kv.x >> 17], __int_as_float(kv.y));
    }
    __syncthreads();
    int node = (b << BSH) + tid;
    if (node < n) {
        float di = rsqrtf(1.0f + acc[tid]);   // +1 = self-loop
        dinv[node] = di;
        p[node] = di * t[node];
    }
}

// ---- K6: s1 agg -> q = dinv*(s1+beta) --------------------------------------
__global__ __launch_bounds__(512) void k_as1(const int2* __restrict__ ep,
                                             const int* __restrict__ bstart,
                                             const float* __restrict__ p,
                                             const float* __restrict__ dinv,
                                             const float* __restrict__ u,
                                             float* __restrict__ q, int n) {
    __shared__ float acc[BNODES];
    int b = blockIdx.x, tid = threadIdx.x;
    acc[tid] = 0.f;
    __syncthreads();
    int j1 = bstart[b + 1];
    for (int j = bstart[b] + tid; j < j1; j += 512) {
        int2 kv = ep[j];
        atomicAdd(&acc[kv.x >> 17], __int_as_float(kv.y) * p[kv.x & 0x1FFFF]);
    }
    __syncthreads();
    int node = (b << BSH) + tid;
    if (node < n) {
        float di = dinv[node];
        float s1 = di * (p[node] + acc[tid]);   // p holds self-loop term dinv*t
        q[node] = di * (s1 + u[CH]);
    }
}

// ---- K7: out agg: out = b2 + dinv*(q + sum w*q[src]) -----------------------
__global__ __launch_bounds__(512) void k_aout(const int2* __restrict__ ep,
                                              const int* __restrict__ bstart,
                                              const float* __restrict__ q,
                                              const float* __restrict__ dinv,
                                              const float* __restrict__ b2,
                                              float* __restrict__ out, int n) {
    __shared__ float acc[BNODES];
    int b = blockIdx.x, tid = threadIdx.x;
    acc[tid] = 0.f;
    __syncthreads();
    int j1 = bstart[b + 1];
    for (int j = bstart[b] + tid; j < j1; j += 512) {
        int2 kv = ep[j];
        atomicAdd(&acc[kv.x >> 17], __int_as_float(kv.y) * q[kv.x & 0x1FFFF]);
    }
    __syncthreads();
    int node = (b << BSH) + tid;
    if (node < n)
        out[node] = b2[0] + dinv[node] * (q[node] + acc[tid]);
}

extern "C" void kernel_launch(void* const* d_in, const int* in_sizes, int n_in,
                              void* d_out, int out_size, void* d_ws, size_t ws_size,
                              hipStream_t stream) {
    const float* x   = (const float*)d_in[0];
    const int*   ei  = (const int*)d_in[1];
    const float* w   = (const float*)d_in[2];
    const float* W1  = (const float*)d_in[3];
    const float* b1  = (const float*)d_in[4];
    const float* W2  = (const float*)d_in[5];
    const float* b2  = (const float*)d_in[6];
    float* out = (float*)d_out;

    const int n     = in_sizes[0] / CH;    // 100000
    const int e_cnt = in_sizes[2];         // 1600000
    const int* row = ei;
    const int* col = ei + e_cnt;

    const int nbuck  = (n + BNODES - 1) >> BSH;         // 196
    const int nchunk = (e_cnt + CHUNK - 1) / CHUNK;     // 196

    // ---- workspace layout (ep first for 8B alignment) ----
    int2*  ep     = (int2*)d_ws;                        // e_cnt int2
    float* u      = (float*)(ep + e_cnt);               // 132
    float* t      = u + 132;                            // n
    float* dinv   = t + n;                              // n
    float* p      = dinv + n;                           // n
    float* q      = p + n;                              // n
    int*   coltot = (int*)(q + n);                      // nbuck
    int*   bstart = coltot + nbuck;                     // nbuck+1
    int*   Ht     = bstart + nbuck + 1;                 // nchunk*nbuck
    int*   Hs     = Ht + (size_t)nchunk * nbuck;        // nchunk*nbuck

    k_uw<<<(CH + 1 + 3) / 4, 256, 0, stream>>>(W1, b1, W2, u);
    k_gemv<<<(n + 7) / 8, 256, 0, stream>>>(x, u, t, n);

    k_hist<<<nchunk, 256, 0, stream>>>(col, Ht, nbuck, e_cnt);
    k_colscan<<<(nbuck + 3) / 4, 256, 0, stream>>>(Ht, Hs, coltot, nchunk, nbuck);
    k_permute<<<nchunk, 256, 0, stream>>>(row, col, w, Hs, coltot, bstart, ep, nbuck, e_cnt);

    k_adeg<<<nbuck, 512, 0, stream>>>(ep, bstart, t, dinv, p, n);
    k_as1<<<nbuck, 512, 0, stream>>>(ep, bstart, p, dinv, u, q, n);
    k_aout<<<nbuck, 512, 0, stream>>>(ep, bstart, q, dinv, b2, out, n);
}